// Round 5
// baseline (189.057 us; speedup 1.0000x reference)
//
#include <hip/hip_runtime.h>
#include <hip/hip_cooperative_groups.h>
#include <math.h>

namespace cg = cooperative_groups;

#define LMAX    6
#define NRAD    20
#define NELEM   4
#define NBATCH  2000
#define NPTS    100000
#define NLMTOT  49
#define NFEAT   69            // 49 Y + 20 rad
#define OUTROW  3920
#define GRID    1024
#define THREADS 256
#define PI_F    3.14159265358979323846f
#define RADK    0.44721359549995793f   // sqrt(2/RC), RC=10
#define INV_RC  0.1f
#define P_OFF   16384         // Pf byte offset inside d_ws (seg uses first 8004 B)

__device__ __forceinline__ void compute_norms(int t, float* sC) {
  if (t < NLMTOT) {
    int lm = t, l = 0;
#pragma unroll
    for (int ll = 1; ll <= LMAX; ++ll) if (lm >= ll * ll) l = ll;
    int m  = lm - l * l - l;
    int am = m < 0 ? -m : m;
    float denom = 1.f;                 // (l+am)!/(l-am)!
    for (int k = l - am + 1; k <= l + am; ++k) denom *= (float)k;
    float nlm = sqrtf((float)(2 * l + 1) / denom);
    sC[lm] = (m == 0) ? nlm : 1.4142135623730951f * nlm;
  }
}

__device__ __forceinline__ void seg_search(int gid, const int* __restrict__ batch_ids,
                                           int* __restrict__ seg) {
  if (gid <= NBATCH) {
    int lo = 0, hi = NPTS;
    while (lo < hi) { int mid = (lo + hi) >> 1; if (batch_ids[mid] < gid) lo = mid + 1; else hi = mid; }
    seg[gid] = lo;
  }
}

// feature-major stores: Pf[f*NPTS + p] — consecutive lanes -> consecutive p (coalesced)
__device__ __forceinline__ void phaseA_point(int p, const float* __restrict__ coords,
                                             const float* __restrict__ sC,
                                             float* __restrict__ Pf) {
  float x = coords[3 * p + 0], y = coords[3 * p + 1], z = coords[3 * p + 2];
  float r    = sqrtf(x * x + y * y + z * z);
  float invr = 1.f / r;
  x *= invr; y *= invr; z *= invr;

  float cs[LMAX + 1], sn[LMAX + 1];
  cs[0] = 1.f; sn[0] = 0.f;
#pragma unroll
  for (int m = 1; m <= LMAX; ++m) {
    cs[m] = cs[m - 1] * x - sn[m - 1] * y;
    sn[m] = sn[m - 1] * x + cs[m - 1] * y;
  }
  float Q[LMAX + 1][LMAX + 1];
  Q[0][0] = 1.f;
#pragma unroll
  for (int m = 1; m <= LMAX; ++m) Q[m][m] = -(float)(2 * m - 1) * Q[m - 1][m - 1];
#pragma unroll
  for (int m = 0; m < LMAX; ++m) Q[m + 1][m] = (float)(2 * m + 1) * z * Q[m][m];
#pragma unroll
  for (int m = 0; m <= LMAX; ++m) {
#pragma unroll
    for (int ll = m + 2; ll <= LMAX; ++ll) {
      Q[ll][m] = ((float)(2 * ll - 1) * z * Q[ll - 1][m]
                - (float)(ll + m - 1) * Q[ll - 2][m]) / (float)(ll - m);
    }
  }
#pragma unroll
  for (int ll = 0; ll <= LMAX; ++ll) {
#pragma unroll
    for (int m = -ll; m <= ll; ++m) {
      int am = m < 0 ? -m : m;
      float v = Q[ll][am] * sC[ll * ll + ll + m];
      if (m < 0)      v *= sn[am];
      else if (m > 0) v *= cs[am];
      Pf[(ll * ll + ll + m) * NPTS + p] = v;
    }
  }
  float a = PI_F * r * INV_RC;
  float s1, c1;
  __sincosf(a, &s1, &c1);
  float twoc = 2.f * c1, sprev = 0.f, scur = s1, scale = RADK * invr;
#pragma unroll
  for (int n = 0; n < NRAD; ++n) {
    Pf[(NLMTOT + n) * NPTS + p] = scale * scur;
    float sx = twoc * scur - sprev; sprev = scur; scur = sx;
  }
}

// one block (4 waves) per batch; wave w = elem w
__device__ __forceinline__ void phaseB_batch(
    int b, int t, const int* __restrict__ elem_ids, const int* __restrict__ seg,
    const float* __restrict__ Pf, float* __restrict__ out,
    float* sMem /* NFEAT*65 floats; reused as sOut[4][980] */, int (*sIdxI)[64])
{
  const int w = t >> 6, lane = t & 63;
  const int tl = lane & 15, tn = lane >> 4;
  const int start = seg[b], end = seg[b + 1];

  float acc[4][5];
#pragma unroll
  for (int i = 0; i < 4; ++i)
#pragma unroll
    for (int j = 0; j < 5; ++j) acc[i][j] = 0.f;

  for (int c = start; c < end; c += 64) {
    int wcnt = end - c; if (wcnt > 64) wcnt = 64;

    bool match = (lane < wcnt) && (elem_ids[c + lane] == w);
    unsigned long long mask = __ballot(match);
    int mcnt = __popcll(mask);
    int slot = __popcll(mask & ((1ULL << lane) - 1ULL));
    if (match) sIdxI[w][slot] = lane;

    // stage all 69 feature rows of this window (coalesced; f uniform per wave-iter)
    for (int idx = t; idx < NFEAT * 64; idx += THREADS) {
      int f = idx >> 6, p = idx & 63;
      if (p < wcnt) sMem[f * 65 + p] = Pf[f * NPTS + c + p];
    }
    __syncthreads();

    for (int k = 0; k < mcnt; ++k) {
      int p = sIdxI[w][k];
      float y0 = sMem[(4 * tl + 0) * 65 + p];
      float y1 = sMem[(4 * tl + 1) * 65 + p];
      float y2 = sMem[(4 * tl + 2) * 65 + p];
      float y3 = sMem[(4 * tl + 3) * 65 + p];
      float r0 = sMem[(NLMTOT + 5 * tn + 0) * 65 + p];
      float r1 = sMem[(NLMTOT + 5 * tn + 1) * 65 + p];
      float r2 = sMem[(NLMTOT + 5 * tn + 2) * 65 + p];
      float r3 = sMem[(NLMTOT + 5 * tn + 3) * 65 + p];
      float r4 = sMem[(NLMTOT + 5 * tn + 4) * 65 + p];
      acc[0][0] += y0 * r0; acc[0][1] += y0 * r1; acc[0][2] += y0 * r2; acc[0][3] += y0 * r3; acc[0][4] += y0 * r4;
      acc[1][0] += y1 * r0; acc[1][1] += y1 * r1; acc[1][2] += y1 * r2; acc[1][3] += y1 * r3; acc[1][4] += y1 * r4;
      acc[2][0] += y2 * r0; acc[2][1] += y2 * r1; acc[2][2] += y2 * r2; acc[2][3] += y2 * r3; acc[2][4] += y2 * r4;
      acc[3][0] += y3 * r0; acc[3][1] += y3 * r1; acc[3][2] += y3 * r2; acc[3][3] += y3 * r3; acc[3][4] += y3 * r4;
    }
    __syncthreads();
  }

  // epilogue: acc -> sOut (per-wave region), then coalesced float4 runs
#pragma unroll
  for (int i = 0; i < 4; ++i) {
    int lm = 4 * tl + i;
    if (lm < NLMTOT) {
      int l = 0;
#pragma unroll
      for (int ll = 1; ll <= LMAX; ++ll) if (lm >= ll * ll) l = ll;
      int fb = 20 * l * l, mi = lm - l * l, nm = 2 * l + 1;
#pragma unroll
      for (int j = 0; j < 5; ++j)
        sMem[w * 980 + fb + (5 * tn + j) * nm + mi] = acc[i][j];
    }
  }
  __syncthreads();

  for (int idx = lane; idx < 245; idx += 64) {
    int f0 = 4 * idx, lw = 0;
#pragma unroll
    for (int ll = 1; ll <= LMAX; ++ll) if (f0 >= 20 * ll * ll) lw = ll;
    long long g = (long long)b * OUTROW + 80 * lw * lw
                + (long long)w * 20 * (2 * lw + 1) + (f0 - 20 * lw * lw);
    *(float4*)(out + g) = *(const float4*)(sMem + w * 980 + f0);
  }
  __syncthreads();   // protect sMem before next batch's staging
}

// ---------- fused cooperative kernel ----------
__global__ __launch_bounds__(THREADS, 4) void sfe_coop(
    const float* __restrict__ coords, const int* __restrict__ elem_ids,
    const int* __restrict__ batch_ids, int* __restrict__ seg,
    float* __restrict__ Pf, float* __restrict__ out)
{
  __shared__ __align__(16) float sMem[NFEAT * 65];
  __shared__ int sIdxI[NELEM][64];
  __shared__ float sC[NLMTOT];
  const int t = threadIdx.x;
  const int gid = blockIdx.x * THREADS + t;

  compute_norms(t, sC);
  seg_search(gid, batch_ids, seg);
  __syncthreads();
  for (int p = gid; p < NPTS; p += GRID * THREADS) phaseA_point(p, coords, sC, Pf);

  cg::this_grid().sync();

  for (int b = blockIdx.x; b < NBATCH; b += GRID)
    phaseB_batch(b, t, elem_ids, seg, Pf, out, sMem, sIdxI);
}

// ---------- non-cooperative fallback ----------
__global__ __launch_bounds__(256) void seg_k(const int* __restrict__ batch_ids,
                                             int* __restrict__ seg) {
  seg_search(blockIdx.x * 256 + threadIdx.x, batch_ids, seg);
}
__global__ __launch_bounds__(256) void featA_k(const float* __restrict__ coords,
                                               float* __restrict__ Pf) {
  __shared__ float sC[NLMTOT];
  compute_norms(threadIdx.x, sC);
  __syncthreads();
  int p = blockIdx.x * 256 + threadIdx.x;
  if (p < NPTS) phaseA_point(p, coords, sC, Pf);
}
__global__ __launch_bounds__(256) void accumB_k(const int* __restrict__ elem_ids,
                                                const int* __restrict__ seg,
                                                const float* __restrict__ Pf,
                                                float* __restrict__ out) {
  __shared__ __align__(16) float sMem[NFEAT * 65];
  __shared__ int sIdxI[NELEM][64];
  phaseB_batch(blockIdx.x, threadIdx.x, elem_ids, seg, Pf, out, sMem, sIdxI);
}

extern "C" void kernel_launch(void* const* d_in, const int* in_sizes, int n_in,
                              void* d_out, int out_size, void* d_ws, size_t ws_size,
                              hipStream_t stream) {
  const float* coords    = (const float*)d_in[0];
  const int*   elem_ids  = (const int*)d_in[1];
  const int*   batch_ids = (const int*)d_in[2];
  float*       out       = (float*)d_out;
  int*         seg       = (int*)d_ws;
  float*       Pf        = (float*)((char*)d_ws + P_OFF);   // [69][NPTS]

  void* args[] = { (void*)&coords, (void*)&elem_ids, (void*)&batch_ids,
                   (void*)&seg, (void*)&Pf, (void*)&out };
  hipError_t err = hipLaunchCooperativeKernel((const void*)sfe_coop,
                                              dim3(GRID), dim3(THREADS),
                                              args, 0, stream);
  if (err != hipSuccess) {
    (void)hipGetLastError();   // clear, take the 3-dispatch path
    seg_k<<<(NBATCH + 256) / 256, 256, 0, stream>>>(batch_ids, seg);
    featA_k<<<(NPTS + 255) / 256, 256, 0, stream>>>(coords, Pf);
    accumB_k<<<NBATCH, 256, 0, stream>>>(elem_ids, seg, Pf, out);
  }
}

// Round 6
// 30.808 us; speedup vs baseline: 6.1367x; 6.1367x over previous
//
#include <hip/hip_runtime.h>
#include <math.h>

#define LMAX   6
#define NRAD   20
#define NELEM  4
#define NBATCH 2000
#define NPTS   100000
#define NLMTOT 49
#define OUTROW 3920
#define PROW   84            // LDS words per point: [0:49 Y][49:52 pad][52+8g+j: rad n=5g+j]
#define PI_F   3.14159265358979323846f
#define RADK   0.44721359549995793f   // sqrt(2/RC), RC=10
#define INV_RC 0.1f

// --- seg[b] = lower_bound(batch_ids, b), b in [0, NBATCH] ---
__global__ __launch_bounds__(256) void seg_kernel(
    const int* __restrict__ batch_ids, int* __restrict__ seg)
{
  int b = blockIdx.x * blockDim.x + threadIdx.x;
  if (b > NBATCH) return;
  int lo = 0, hi = NPTS;
  while (lo < hi) { int mid = (lo + hi) >> 1; if (batch_ids[mid] < b) lo = mid + 1; else hi = mid; }
  seg[b] = lo;
}

// --- fused: one block per batch; wave w accumulates elem w ---
__global__ __launch_bounds__(256) void sfe_kernel(
    const float* __restrict__ coords,
    const int*   __restrict__ elem_ids,
    const int*   __restrict__ seg,
    float*       __restrict__ out)
{
  const int b    = blockIdx.x;
  const int t    = threadIdx.x;
  const int w    = t >> 6;       // wave = elem
  const int lane = t & 63;
  const int tl   = lane & 15;    // lm tile: {4tl..4tl+3}
  const int tn   = lane >> 4;    // n  tile: {5tn..5tn+4}

  __shared__ __align__(16) float sMem[64 * PROW];  // 21 KB: sP[64][84]; reused as sOut[4][980]
  __shared__ int   sIdx[NELEM][64];
  __shared__ float sC[NLMTOT];

  if (t < NLMTOT) {
    int lm = t, l = 0;
#pragma unroll
    for (int ll = 1; ll <= LMAX; ++ll) if (lm >= ll * ll) l = ll;
    int m  = lm - l * l - l;
    int am = m < 0 ? -m : m;
    float denom = 1.f;
    for (int k = l - am + 1; k <= l + am; ++k) denom *= (float)k;
    float nlm = sqrtf((float)(2 * l + 1) / denom);
    sC[lm] = (m == 0) ? nlm : 1.4142135623730951f * nlm;
  }
  __syncthreads();

  const int start = seg[b], end = seg[b + 1];

  float acc[4][5];
#pragma unroll
  for (int i = 0; i < 4; ++i)
#pragma unroll
    for (int j = 0; j < 5; ++j) acc[i][j] = 0.f;

  for (int c = start; c < end; c += 64) {
    int cnt = end - c; if (cnt > 64) cnt = 64;

    // --- stage SH+rad: 16 lanes of each wave, one point per thread ---
    int pl = w * 16 + tl;                       // point slot handled by this thread
    if (lane < 16 && pl < cnt) {
      int p = c + pl;
      float x = coords[3 * p + 0], y = coords[3 * p + 1], z = coords[3 * p + 2];
      float r    = sqrtf(x * x + y * y + z * z);
      float invr = 1.f / r;
      x *= invr; y *= invr; z *= invr;

      float cs[LMAX + 1], sn[LMAX + 1];
      cs[0] = 1.f; sn[0] = 0.f;
#pragma unroll
      for (int m = 1; m <= LMAX; ++m) {
        cs[m] = cs[m - 1] * x - sn[m - 1] * y;
        sn[m] = sn[m - 1] * x + cs[m - 1] * y;
      }
      float Q[LMAX + 1][LMAX + 1];
      Q[0][0] = 1.f;
#pragma unroll
      for (int m = 1; m <= LMAX; ++m) Q[m][m] = -(float)(2 * m - 1) * Q[m - 1][m - 1];
#pragma unroll
      for (int m = 0; m < LMAX; ++m) Q[m + 1][m] = (float)(2 * m + 1) * z * Q[m][m];
#pragma unroll
      for (int m = 0; m <= LMAX; ++m) {
#pragma unroll
        for (int ll = m + 2; ll <= LMAX; ++ll) {
          Q[ll][m] = ((float)(2 * ll - 1) * z * Q[ll - 1][m]
                    - (float)(ll + m - 1) * Q[ll - 2][m]) / (float)(ll - m);
        }
      }
      float* row = sMem + pl * PROW;
#pragma unroll
      for (int ll = 0; ll <= LMAX; ++ll) {
#pragma unroll
        for (int m = -ll; m <= ll; ++m) {
          int am = m < 0 ? -m : m;
          float v = Q[ll][am] * sC[ll * ll + ll + m];
          if (m < 0)      v *= sn[am];
          else if (m > 0) v *= cs[am];
          row[ll * ll + ll + m] = v;
        }
      }
      float a = PI_F * r * INV_RC;
      float s1, c1;
      __sincosf(a, &s1, &c1);
      float twoc = 2.f * c1, sprev = 0.f, scur = s1, scale = RADK * invr;
#pragma unroll
      for (int n = 0; n < NRAD; ++n) {
        row[52 + 8 * (n / 5) + (n % 5)] = scale * scur;
        float sx = twoc * scur - sprev; sprev = scur; scur = sx;
      }
    }

    // --- per-wave ballot-compact of this wave's elem (overlaps SH latency) ---
    bool match = (lane < cnt) && (elem_ids[c + lane] == w);
    unsigned long long mask = __ballot(match);
    int mcnt = __popcll(mask);
    int slot = __popcll(mask & ((1ULL << lane) - 1ULL));
    if (match) sIdx[w][slot] = lane;
    __syncthreads();

    // --- accumulate: 2x ds_read_b128 + 1x b32 feed 20 FMAs per matched point ---
    for (int k = 0; k < mcnt; ++k) {
      const float* row = sMem + sIdx[w][k] * PROW;
      float4 yv = *(const float4*)(row + 4 * tl);
      float4 ra = *(const float4*)(row + 52 + 8 * tn);
      float  r4 = row[52 + 8 * tn + 4];
      float yy[4] = {yv.x, yv.y, yv.z, yv.w};
      float rr[5] = {ra.x, ra.y, ra.z, ra.w, r4};
#pragma unroll
      for (int i = 0; i < 4; ++i)
#pragma unroll
        for (int j = 0; j < 5; ++j)
          acc[i][j] += yy[i] * rr[j];
    }
    __syncthreads();
  }

  // --- epilogue (wave-local): acc -> sOut[w][980] feature-ordered, then float4 runs ---
  float* sOut = sMem + w * 980;
#pragma unroll
  for (int i = 0; i < 4; ++i) {
    int lm = 4 * tl + i;
    if (lm < NLMTOT) {
      int l = 0;
#pragma unroll
      for (int ll = 1; ll <= LMAX; ++ll) if (lm >= ll * ll) l = ll;
      int fb = 20 * l * l, mi = lm - l * l, nm = 2 * l + 1;
#pragma unroll
      for (int j = 0; j < 5; ++j)
        sOut[fb + (5 * tn + j) * nm + mi] = acc[i][j];
    }
  }
  // same-wave LDS write->read: compiler inserts lgkmcnt; no cross-wave barrier needed
  for (int idx = lane; idx < 245; idx += 64) {
    int f0 = 4 * idx, lw = 0;
#pragma unroll
    for (int ll = 1; ll <= LMAX; ++ll) if (f0 >= 20 * ll * ll) lw = ll;
    long long g = (long long)b * OUTROW + 80 * lw * lw
                + (long long)w * 20 * (2 * lw + 1) + (f0 - 20 * lw * lw);
    *(float4*)(out + g) = *(const float4*)(sOut + f0);
  }
}

extern "C" void kernel_launch(void* const* d_in, const int* in_sizes, int n_in,
                              void* d_out, int out_size, void* d_ws, size_t ws_size,
                              hipStream_t stream) {
  const float* coords    = (const float*)d_in[0];
  const int*   elem_ids  = (const int*)d_in[1];
  const int*   batch_ids = (const int*)d_in[2];
  float*       out       = (float*)d_out;
  int*         seg       = (int*)d_ws;   // NBATCH+1 ints

  seg_kernel<<<(NBATCH + 1 + 255) / 256, 256, 0, stream>>>(batch_ids, seg);
  sfe_kernel<<<NBATCH, 256, 0, stream>>>(coords, elem_ids, seg, out);
}

// Round 7
// 29.661 us; speedup vs baseline: 6.3739x; 1.0386x over previous
//
#include <hip/hip_runtime.h>
#include <math.h>

#define LMAX   6
#define NRAD   20
#define NELEM  4
#define NBATCH 2000
#define NPTS   100000
#define NLMTOT 49
#define OUTROW 3920
#define PROW   72            // LDS words/point: [0:49 Y][49:52 pad][52:72 rad]
#define PI_F   3.14159265358979323846f
#define RADK   0.44721359549995793f   // sqrt(2/RC), RC=10
#define INV_RC 0.1f

// --- single fused kernel: one block per batch; wave w accumulates elem w ---
__global__ __launch_bounds__(256) void sfe_kernel(
    const float* __restrict__ coords,
    const int*   __restrict__ elem_ids,
    const int*   __restrict__ batch_ids,
    float*       __restrict__ out)
{
  const int b    = blockIdx.x;
  const int t    = threadIdx.x;
  const int w    = t >> 6;       // wave = elem
  const int lane = t & 63;
  const int tl   = lane & 15;    // lm tile: {4tl..4tl+3}
  const int tn   = lane >> 4;    // n  tile: {5tn..5tn+4}

  __shared__ __align__(16) float sMem[64 * PROW];  // 18.4 KB; reused as sOut[4][980]
  __shared__ int   sIdx[NELEM][64];
  __shared__ float sC[NLMTOT];
  __shared__ int   sRange[2];

  // per-block range via 2-lane binary search (overlaps sC compute below)
  if (t < 2) {
    int target = b + t;
    int lo = 0, hi = NPTS;
    while (lo < hi) { int mid = (lo + hi) >> 1; if (batch_ids[mid] < target) lo = mid + 1; else hi = mid; }
    sRange[t] = lo;
  }
  if (t >= 64 && t < 64 + NLMTOT) {
    int lm = t - 64, l = 0;
#pragma unroll
    for (int ll = 1; ll <= LMAX; ++ll) if (lm >= ll * ll) l = ll;
    int m  = lm - l * l - l;
    int am = m < 0 ? -m : m;
    float denom = 1.f;
    for (int k = l - am + 1; k <= l + am; ++k) denom *= (float)k;
    float nlm = sqrtf((float)(2 * l + 1) / denom);
    sC[lm] = (m == 0) ? nlm : 1.4142135623730951f * nlm;
  }
  __syncthreads();

  const int start = sRange[0], end = sRange[1];

  float acc[4][5];
#pragma unroll
  for (int i = 0; i < 4; ++i)
#pragma unroll
    for (int j = 0; j < 5; ++j) acc[i][j] = 0.f;

  for (int c = start; c < end; c += 64) {
    int cnt = end - c; if (cnt > 64) cnt = 64;

    // --- stage SH+rad: 16 lanes of each wave, one point per thread ---
    int pl = w * 16 + tl;
    if (lane < 16 && pl < cnt) {
      int p = c + pl;
      float x = coords[3 * p + 0], y = coords[3 * p + 1], z = coords[3 * p + 2];
      float r    = sqrtf(x * x + y * y + z * z);
      float invr = 1.f / r;
      x *= invr; y *= invr; z *= invr;

      float cs[LMAX + 1], sn[LMAX + 1];
      cs[0] = 1.f; sn[0] = 0.f;
#pragma unroll
      for (int m = 1; m <= LMAX; ++m) {
        cs[m] = cs[m - 1] * x - sn[m - 1] * y;
        sn[m] = sn[m - 1] * x + cs[m - 1] * y;
      }
      float Q[LMAX + 1][LMAX + 1];
      Q[0][0] = 1.f;
#pragma unroll
      for (int m = 1; m <= LMAX; ++m) Q[m][m] = -(float)(2 * m - 1) * Q[m - 1][m - 1];
#pragma unroll
      for (int m = 0; m < LMAX; ++m) Q[m + 1][m] = (float)(2 * m + 1) * z * Q[m][m];
#pragma unroll
      for (int m = 0; m <= LMAX; ++m) {
#pragma unroll
        for (int ll = m + 2; ll <= LMAX; ++ll) {
          Q[ll][m] = ((float)(2 * ll - 1) * z * Q[ll - 1][m]
                    - (float)(ll + m - 1) * Q[ll - 2][m]) / (float)(ll - m);
        }
      }
      float* row = sMem + pl * PROW;
#pragma unroll
      for (int ll = 0; ll <= LMAX; ++ll) {
#pragma unroll
        for (int m = -ll; m <= ll; ++m) {
          int am = m < 0 ? -m : m;
          float v = Q[ll][am] * sC[ll * ll + ll + m];
          if (m < 0)      v *= sn[am];
          else if (m > 0) v *= cs[am];
          row[ll * ll + ll + m] = v;
        }
      }
      float a = PI_F * r * INV_RC;
      float s1, c1;
      __sincosf(a, &s1, &c1);
      float twoc = 2.f * c1, sprev = 0.f, scur = s1, scale = RADK * invr;
#pragma unroll
      for (int n = 0; n < NRAD; ++n) {
        row[52 + n] = scale * scur;
        float sx = twoc * scur - sprev; sprev = scur; scur = sx;
      }
    }

    // --- per-wave ballot-compact of this wave's elem ---
    bool match = (lane < cnt) && (elem_ids[c + lane] == w);
    unsigned long long mask = __ballot(match);
    int mcnt = __popcll(mask);
    int slot = __popcll(mask & ((1ULL << lane) - 1ULL));
    if (match) sIdx[w][slot] = lane;
    __syncthreads();

    // --- accumulate: b128 (Y) + 5x b32 (rad) feed 20 FMAs per matched point ---
    for (int k = 0; k < mcnt; ++k) {
      const float* row = sMem + sIdx[w][k] * PROW;
      float4 yv = *(const float4*)(row + 4 * tl);
      float  r0 = row[52 + 5 * tn + 0];
      float  r1 = row[52 + 5 * tn + 1];
      float  r2 = row[52 + 5 * tn + 2];
      float  r3 = row[52 + 5 * tn + 3];
      float  r4 = row[52 + 5 * tn + 4];
      float yy[4] = {yv.x, yv.y, yv.z, yv.w};
      float rr[5] = {r0, r1, r2, r3, r4};
#pragma unroll
      for (int i = 0; i < 4; ++i)
#pragma unroll
        for (int j = 0; j < 5; ++j)
          acc[i][j] += yy[i] * rr[j];
    }
    __syncthreads();
  }

  // --- epilogue (wave-local): acc -> sOut[w][980], then coalesced float4 runs ---
  float* sOut = sMem + w * 980;
#pragma unroll
  for (int i = 0; i < 4; ++i) {
    int lm = 4 * tl + i;
    if (lm < NLMTOT) {
      int l = 0;
#pragma unroll
      for (int ll = 1; ll <= LMAX; ++ll) if (lm >= ll * ll) l = ll;
      int fb = 20 * l * l, mi = lm - l * l, nm = 2 * l + 1;
#pragma unroll
      for (int j = 0; j < 5; ++j)
        sOut[fb + (5 * tn + j) * nm + mi] = acc[i][j];
    }
  }
  for (int idx = lane; idx < 245; idx += 64) {
    int f0 = 4 * idx, lw = 0;
#pragma unroll
    for (int ll = 1; ll <= LMAX; ++ll) if (f0 >= 20 * ll * ll) lw = ll;
    long long g = (long long)b * OUTROW + 80 * lw * lw
                + (long long)w * 20 * (2 * lw + 1) + (f0 - 20 * lw * lw);
    *(float4*)(out + g) = *(const float4*)(sOut + f0);
  }
}

extern "C" void kernel_launch(void* const* d_in, const int* in_sizes, int n_in,
                              void* d_out, int out_size, void* d_ws, size_t ws_size,
                              hipStream_t stream) {
  const float* coords    = (const float*)d_in[0];
  const int*   elem_ids  = (const int*)d_in[1];
  const int*   batch_ids = (const int*)d_in[2];
  float*       out       = (float*)d_out;
  sfe_kernel<<<NBATCH, 256, 0, stream>>>(coords, elem_ids, batch_ids, out);
}

// Round 8
// 24.737 us; speedup vs baseline: 7.6427x; 1.1991x over previous
//
#include <hip/hip_runtime.h>
#include <math.h>

#define LMAX   6
#define NRAD   20
#define NELEM  4
#define NBATCH 2000
#define NPTS   100000
#define NLMTOT 49
#define OUTROW 3920
#define PROW   76            // LDS words/pt: [0:49 Y][49:52 pad][52+6g+j: rad n=5g+j, j<5]
#define PI_F   3.14159265358979323846f
#define RADK   0.44721359549995793f   // sqrt(2/RC), RC=10
#define INV_RC 0.1f

// --- single fused kernel: one block per batch; wave w accumulates elem w ---
__global__ __launch_bounds__(256) void sfe_kernel(
    const float* __restrict__ coords,
    const int*   __restrict__ elem_ids,
    const int*   __restrict__ batch_ids,
    float*       __restrict__ out)
{
  const int b    = blockIdx.x;
  const int t    = threadIdx.x;
  const int w    = t >> 6;       // wave = elem
  const int lane = t & 63;
  const int tl   = lane & 15;    // lm tile: {4tl..4tl+3}
  const int tn   = lane >> 4;    // n  tile: {5tn..5tn+4}

  __shared__ __align__(16) float sMem[64 * PROW];  // 19.5 KB; reused as sOut[4][980]
  __shared__ float sC[NLMTOT];
  __shared__ int   sRange[2];

  // --- wave 0: 4-level 32-ary parallel lower_bound for b (lanes 0-31) and b+1 (32-63) ---
  if (t < 64) {
    const int half = t >> 5, j = t & 31;
    const int tgt  = b + half;
    const unsigned long long hm = half ? 0xFFFFFFFF00000000ULL : 0x00000000FFFFFFFFULL;
    int base = 0;
    int S = 3125;
#pragma unroll
    for (int lev = 0; lev < 4; ++lev) {
      int pos = base + j * S;
      int val = (pos < NPTS) ? batch_ids[pos] : 0x7FFFFFFF;
      unsigned long long mb = __ballot(val < tgt) & hm;
      int cnt = __popcll(mb);
      if (S == 1)       base += cnt;                 // final: exact
      else if (cnt > 0) base += (cnt - 1) * S + 1;   // range shrinks to S
      S = (lev == 0) ? 98 : (lev == 1) ? 4 : 1;
    }
    if (j == 0) sRange[half] = base;
  }
  // --- wave 1: normalization constants ---
  if (t >= 64 && t < 64 + NLMTOT) {
    int lm = t - 64, l = 0;
#pragma unroll
    for (int ll = 1; ll <= LMAX; ++ll) if (lm >= ll * ll) l = ll;
    int m  = lm - l * l - l;
    int am = m < 0 ? -m : m;
    float denom = 1.f;
    for (int k = l - am + 1; k <= l + am; ++k) denom *= (float)k;
    float nlm = sqrtf((float)(2 * l + 1) / denom);
    sC[lm] = (m == 0) ? nlm : 1.4142135623730951f * nlm;
  }
  __syncthreads();

  const int start = sRange[0], end = sRange[1];

  float acc[4][5];
#pragma unroll
  for (int i = 0; i < 4; ++i)
#pragma unroll
    for (int j = 0; j < 5; ++j) acc[i][j] = 0.f;

  for (int c = start; c < end; c += 64) {
    int cnt = end - c; if (cnt > 64) cnt = 64;

    // --- stage SH+rad: wave 0 only, ALL 64 lanes, one point per lane ---
    if (t < 64 && lane < cnt) {
      int p = c + lane;
      float x = coords[3 * p + 0], y = coords[3 * p + 1], z = coords[3 * p + 2];
      float r    = sqrtf(x * x + y * y + z * z);
      float invr = 1.f / r;
      x *= invr; y *= invr; z *= invr;

      float cs[LMAX + 1], sn[LMAX + 1];
      cs[0] = 1.f; sn[0] = 0.f;
#pragma unroll
      for (int m = 1; m <= LMAX; ++m) {
        cs[m] = cs[m - 1] * x - sn[m - 1] * y;
        sn[m] = sn[m - 1] * x + cs[m - 1] * y;
      }
      float Q[LMAX + 1][LMAX + 1];
      Q[0][0] = 1.f;
#pragma unroll
      for (int m = 1; m <= LMAX; ++m) Q[m][m] = -(float)(2 * m - 1) * Q[m - 1][m - 1];
#pragma unroll
      for (int m = 0; m < LMAX; ++m) Q[m + 1][m] = (float)(2 * m + 1) * z * Q[m][m];
#pragma unroll
      for (int m = 0; m <= LMAX; ++m) {
#pragma unroll
        for (int ll = m + 2; ll <= LMAX; ++ll) {
          Q[ll][m] = ((float)(2 * ll - 1) * z * Q[ll - 1][m]
                    - (float)(ll + m - 1) * Q[ll - 2][m]) / (float)(ll - m);
        }
      }
      float* row = sMem + lane * PROW;
#pragma unroll
      for (int ll = 0; ll <= LMAX; ++ll) {
#pragma unroll
        for (int m = -ll; m <= ll; ++m) {
          int am = m < 0 ? -m : m;
          float v = Q[ll][am] * sC[ll * ll + ll + m];
          if (m < 0)      v *= sn[am];
          else if (m > 0) v *= cs[am];
          row[ll * ll + ll + m] = v;
        }
      }
      // rad: sin(n*a) Chebyshev; tile of 6: word 52+6g+j holds n=5g+j (j<5)
      float a = PI_F * r * INV_RC;
      float s1, c1;
      __sincosf(a, &s1, &c1);
      float twoc = 2.f * c1, sprev = 0.f, scur = s1, scale = RADK * invr;
#pragma unroll
      for (int n = 0; n < NRAD; ++n) {
        row[52 + 6 * (n / 5) + (n % 5)] = scale * scur;
        float sx = twoc * scur - sprev; sprev = scur; scur = sx;
      }
    }

    // --- per-wave ballot of this wave's elem (no LDS index list) ---
    bool match = (lane < cnt) && (elem_ids[c + lane] == w);
    unsigned long long mask = __ballot(match);
    __syncthreads();

    // --- accumulate: walk mask bits; b128 (Y) + 2x b64 + b32 (rad), 20 FMAs/pt ---
    for (unsigned long long mm = mask; mm; mm &= mm - 1) {
      int p = (int)__ffsll(mm) - 1;
      const float* row = sMem + p * PROW;
      float4 yv = *(const float4*)(row + 4 * tl);
      float2 ra = *(const float2*)(row + 52 + 6 * tn);
      float2 rb = *(const float2*)(row + 52 + 6 * tn + 2);
      float  r4 = row[52 + 6 * tn + 4];
      float yy[4] = {yv.x, yv.y, yv.z, yv.w};
      float rr[5] = {ra.x, ra.y, rb.x, rb.y, r4};
#pragma unroll
      for (int i = 0; i < 4; ++i)
#pragma unroll
        for (int j = 0; j < 5; ++j)
          acc[i][j] += yy[i] * rr[j];
    }
    __syncthreads();
  }

  // --- epilogue (wave-local): acc -> sOut[w][980], then coalesced float4 runs ---
  float* sOut = sMem + w * 980;
#pragma unroll
  for (int i = 0; i < 4; ++i) {
    int lm = 4 * tl + i;
    if (lm < NLMTOT) {
      int l = 0;
#pragma unroll
      for (int ll = 1; ll <= LMAX; ++ll) if (lm >= ll * ll) l = ll;
      int fb = 20 * l * l, mi = lm - l * l, nm = 2 * l + 1;
#pragma unroll
      for (int j = 0; j < 5; ++j)
        sOut[fb + (5 * tn + j) * nm + mi] = acc[i][j];
    }
  }
  for (int idx = lane; idx < 245; idx += 64) {
    int f0 = 4 * idx, lw = 0;
#pragma unroll
    for (int ll = 1; ll <= LMAX; ++ll) if (f0 >= 20 * ll * ll) lw = ll;
    long long g = (long long)b * OUTROW + 80 * lw * lw
                + (long long)w * 20 * (2 * lw + 1) + (f0 - 20 * lw * lw);
    *(float4*)(out + g) = *(const float4*)(sOut + f0);
  }
}

extern "C" void kernel_launch(void* const* d_in, const int* in_sizes, int n_in,
                              void* d_out, int out_size, void* d_ws, size_t ws_size,
                              hipStream_t stream) {
  const float* coords    = (const float*)d_in[0];
  const int*   elem_ids  = (const int*)d_in[1];
  const int*   batch_ids = (const int*)d_in[2];
  float*       out       = (float*)d_out;
  sfe_kernel<<<NBATCH, 256, 0, stream>>>(coords, elem_ids, batch_ids, out);
}